// Round 9
// baseline (208.766 us; speedup 1.0000x reference)
//
#include <hip/hip_runtime.h>
#include <math.h>

#define NN 50000
#define NE 800000
#define FIN 128
#define HID 64
#define HEADS 4
#define C1 256   // HEADS*HID
#define CLS 40
#define EPSF 1e-16f

// bucket sort params: 98 buckets of 512 dst nodes each
#define NB 98
#define BSH 9
#define BSTRIDE 9216     // > max bucket count (mean 8192, +11 sigma), 64B-aligned
#define NBLK_B 1250
#define CHUNK 640        // 1250*640 == NE exactly; halved vs r7 (latency-bound)
#define NBLK_G 391       // ceil(50000/128) gemm1 double-tiles

typedef __attribute__((ext_vector_type(8))) short bf16x8;
typedef __attribute__((ext_vector_type(4))) float f32x4;
typedef __attribute__((ext_vector_type(2))) float f32x2;

__device__ __forceinline__ unsigned short f2bf(float f) {
    unsigned int u = __float_as_uint(f);
    unsigned int r = (u + 0x7fffu + ((u >> 16) & 1u)) >> 16;   // RNE
    return (unsigned short)r;
}
__device__ __forceinline__ float bflo(unsigned int u) { return __uint_as_float(u << 16); }
__device__ __forceinline__ float bfhi(unsigned int u) { return __uint_as_float(u & 0xffff0000u); }
__device__ __forceinline__ unsigned char f2fp8(float v) {
    int pk = __builtin_amdgcn_cvt_pk_fp8_f32(v, v, 0, false);
    return (unsigned char)(pk & 0xff);
}
__device__ __forceinline__ float lrelu(float e) { return e > 0.f ? e : 0.2f * e; }

// ---------------- two-level bucket sort of edges by dst ----------------
// Level 1: partition edges into 98 coarse buckets; in-LDS counting sort by
// bucket before the global write so stage writes are coalesced line bursts.
// 1250 blocks x 640 edges (was 625x1280): the kernel is latency-bound on
// LDS-atomic passes + barriers (r2 counters: Occ 20%, VALU 1%, HBM 9%), so
// halve per-block serial work and double parallelism.
// Blocks 0..10 additionally perform the one-time W1/W2 -> MFMA-fragment
// conversion; block 0 also zeroes the ssrc tail pad (replaces a memset).
__global__ __launch_bounds__(512) void k_bucket(const int* __restrict__ ei,
                                                int* __restrict__ gcur,
                                                unsigned int* __restrict__ stage,
                                                const float* __restrict__ W1,
                                                const float* __restrict__ W2,
                                                unsigned short* __restrict__ wB1,
                                                unsigned short* __restrict__ wB2,
                                                int* __restrict__ ssrc_pad) {
    __shared__ unsigned int lchunk[CHUNK];
    __shared__ unsigned int lsort[CHUNK];
    __shared__ int lhist[128];
    __shared__ int sbuf[128];
    __shared__ int lstart[128];
    __shared__ int lbase[128];
    __shared__ int lcur[128];
    int t = threadIdx.x;

    // folded-in weight conversion (independent work, overlaps LDS phase)
    if (blockIdx.x < 11) {
        int tw = blockIdx.x * 512 + t;
        if (blockIdx.x == 0 && t >= 448) ssrc_pad[t - 448] = 0;  // ssrc[NE..NE+63]
        if (tw < 4096) {
            int tn = tw >> 8;
            int kc = (tw >> 6) & 3;
            int lw = tw & 63;
            int n = tn * 16 + (lw & 15);
            int k0 = kc * 32 + (lw >> 4) * 8;
            unsigned short* o = wB1 + (size_t)tw * 8;
#pragma unroll
            for (int j = 0; j < 8; j++) o[j] = f2bf(W1[(size_t)(k0 + j) * C1 + n]);
        } else if (tw < 4096 + 1536) {
            int u = tw - 4096;
            int tn = u >> 9;
            int kc = (u >> 6) & 7;
            int lw = u & 63;
            int n = tn * 16 + (lw & 15);
            int k0 = kc * 32 + (lw >> 4) * 8;
            unsigned short* o = wB2 + (size_t)u * 8;
#pragma unroll
            for (int j = 0; j < 8; j++)
                o[j] = (n < CLS) ? f2bf(W2[(size_t)(k0 + j) * CLS + n]) : (unsigned short)0;
        }
    }

    int e0 = blockIdx.x * CHUNK;
    if (t < 128) lhist[t] = 0;
    __syncthreads();
    for (int j = t; j < CHUNK; j += 512) {
        int s = ei[e0 + j];
        int d = ei[NE + e0 + j];
        int b = d >> BSH;
        atomicAdd(&lhist[b], 1);
        lchunk[j] = (unsigned int)s | ((unsigned int)(d & 511) << 16) |
                    ((unsigned int)b << 25);
    }
    __syncthreads();
    // exclusive scan of the 128 bins (Hillis-Steele in LDS)
    if (t < 128) sbuf[t] = lhist[t];
    __syncthreads();
    for (int d = 1; d < 128; d <<= 1) {
        int x = (t < 128 && t >= d) ? sbuf[t - d] : 0;
        __syncthreads();
        if (t < 128) sbuf[t] += x;
        __syncthreads();
    }
    if (t < 128) {
        int excl = sbuf[t] - lhist[t];
        lstart[t] = excl;
        lcur[t] = excl;
        if (t < NB) lbase[t] = atomicAdd(&gcur[t], lhist[t]);
    }
    __syncthreads();
    // in-LDS counting sort by bucket
    for (int j = t; j < CHUNK; j += 512) {
        unsigned int pk = lchunk[j];
        int b = pk >> 25;
        int pos = atomicAdd(&lcur[b], 1);
        lsort[pos] = pk;
    }
    __syncthreads();
    // coalesced write-out: consecutive j -> consecutive dest within a run
    for (int j = t; j < CHUNK; j += 512) {
        unsigned int pk = lsort[j];
        int b = pk >> 25;
        int dest = lbase[b] + (j - lstart[b]);
        stage[(size_t)b * BSTRIDE + dest] = pk & 0x01FFFFFFu;
    }
}

// ---------------- fused bsort + gemm1 (independent work, one dispatch) ----
// Blocks 0..NB-1: per-bucket LDS counting sort (bsort body, 512 threads).
// Blocks NB..NB+390: TWO copies of the verified 256-thread gemm1 tile.
__global__ __launch_bounds__(512) void k_bsg(const unsigned int* __restrict__ stage,
                                             const int* __restrict__ gcur,
                                             int* __restrict__ offs,
                                             int* __restrict__ ssrc,
                                             const float* __restrict__ x,
                                             const unsigned short* __restrict__ wB,
                                             const float* __restrict__ aws,
                                             const float* __restrict__ awd,
                                             unsigned char* __restrict__ h1f8,
                                             float* __restrict__ as1,
                                             float* __restrict__ ad1) {
    __shared__ union SM {
        struct { int lhist[512]; int cur[512]; int sbuf[128]; } b;
        struct { uint4 Af[2][4][4][64]; } g;   // 32 KB
    } sm;

    if (blockIdx.x < NB) {
        // ---------------- bsort body ----------------
        int t = threadIdx.x;
        int b = blockIdx.x;
        int cnt = gcur[b];
        const unsigned int* sp = stage + (size_t)b * BSTRIDE;
        if (t < 128) sm.b.sbuf[t] = (t < NB) ? gcur[t] : 0;
        sm.b.lhist[t] = 0;
        __syncthreads();
        for (int d = 1; d < 128; d <<= 1) {
            int xv = (t < 128 && t >= d) ? sm.b.sbuf[t - d] : 0;
            __syncthreads();
            if (t < 128) sm.b.sbuf[t] += xv;
            __syncthreads();
        }
        int gbase = sm.b.sbuf[b] - cnt;
        for (int j = t; j < cnt; j += 512) atomicAdd(&sm.b.lhist[(sp[j] >> 16) & 511], 1);
        __syncthreads();
        if (t < 64) {
            int base = t * 8;
            int vals[8];
            int run = 0;
#pragma unroll
            for (int j = 0; j < 8; j++) { int v = sm.b.lhist[base + j]; vals[j] = run; run += v; }
            int sc = run;
#pragma unroll
            for (int d = 1; d < 64; d <<= 1) { int u = __shfl_up(sc, d); if (t >= d) sc += u; }
            int excl = sc - run;
#pragma unroll
            for (int j = 0; j < 8; j++) sm.b.cur[base + j] = excl + vals[j];
        }
        __syncthreads();
        offs[(b << BSH) + t] = gbase + sm.b.cur[t];
        __syncthreads();
        for (int j = t; j < cnt; j += 512) {
            unsigned int v = sp[j];
            int dl = (v >> 16) & 511;
            int pos = atomicAdd(&sm.b.cur[dl], 1);
            ssrc[gbase + pos] = (int)(v & 0xFFFFu);
        }
        return;
    }

    // ---------------- gemm1 body (two 64-row tiles per block) ----------------
    int half = threadIdx.x >> 8;
    int t = threadIdx.x & 255;
    int m0 = ((blockIdx.x - NB) * 2 + half) * 64;
    int l = t & 63;
    int wv = t >> 6;                 // wave-quarter within the half = head

    // prefetch the wave's 16 B-fragments (independent; overlap staging)
    bf16x8 bf[4][4];
    const bf16x8* wb = (const bf16x8*)wB + l;
#pragma unroll
    for (int tn = 0; tn < 4; tn++)
#pragma unroll
        for (int kc = 0; kc < 4; kc++)
            bf[tn][kc] = wb[(((wv * 4 + tn) * 4 + kc)) * 64];

#pragma unroll
    for (int i = 0; i < 8; i++) {
        int g = i * 256 + t;
        int row = g >> 5;
        int c4 = g & 31;
        int grow = m0 + row;
        if (grow >= NN) grow = NN - 1;
        float4 v = *(const float4*)(x + (size_t)grow * FIN + c4 * 4);
        uint2 pk;
        pk.x = (unsigned int)f2bf(v.x) | ((unsigned int)f2bf(v.y) << 16);
        pk.y = (unsigned int)f2bf(v.z) | ((unsigned int)f2bf(v.w) << 16);
        int kc = c4 >> 3;
        int rem = (c4 & 7) * 4;
        int q = rem >> 3;
        int hh = (rem >> 2) & 1;
        int ll = q * 16 + (row & 15);
        int mt = row >> 4;
        ((uint2*)&sm.g.Af[half][mt][kc][ll])[hh] = pk;
    }
    __syncthreads();

    int q = l >> 4;
    int c = l & 15;

#pragma unroll
    for (int mt = 0; mt < 4; mt++) {
        bf16x8 a[4];
#pragma unroll
        for (int kc = 0; kc < 4; kc++) a[kc] = *(const bf16x8*)&sm.g.Af[half][mt][kc][l];

        f32x4 acc[4];
#pragma unroll
        for (int tn = 0; tn < 4; tn++) acc[tn] = (f32x4){0.f, 0.f, 0.f, 0.f};
#pragma unroll
        for (int tn = 0; tn < 4; tn++) {
            acc[tn] = __builtin_amdgcn_mfma_f32_16x16x32_bf16(a[0], bf[tn][0], acc[tn], 0, 0, 0);
            acc[tn] = __builtin_amdgcn_mfma_f32_16x16x32_bf16(a[1], bf[tn][1], acc[tn], 0, 0, 0);
            acc[tn] = __builtin_amdgcn_mfma_f32_16x16x32_bf16(a[2], bf[tn][2], acc[tn], 0, 0, 0);
            acc[tn] = __builtin_amdgcn_mfma_f32_16x16x32_bf16(a[3], bf[tn][3], acc[tn], 0, 0, 0);
        }

        int row0 = m0 + mt * 16 + q * 4;
        float ps[4] = {0.f, 0.f, 0.f, 0.f}, pd[4] = {0.f, 0.f, 0.f, 0.f};
#pragma unroll
        for (int tn = 0; tn < 4; tn++) {
            int col = wv * 64 + tn * 16 + c;
            float wsv = aws[col];
            float wdv = awd[col];
#pragma unroll
            for (int r = 0; r < 4; r++) {
                float v = acc[tn][r];
                int row = row0 + r;
                if (row < NN) h1f8[(size_t)row * C1 + col] = f2fp8(v);
                ps[r] = fmaf(v, wsv, ps[r]);
                pd[r] = fmaf(v, wdv, pd[r]);
            }
        }
#pragma unroll
        for (int r = 0; r < 4; r++) {
            float a_ = ps[r], d_ = pd[r];
#pragma unroll
            for (int s = 1; s < 16; s <<= 1) {
                a_ += __shfl_xor(a_, s);
                d_ += __shfl_xor(d_, s);
            }
            int row = row0 + r;
            if (c == 0 && row < NN) {
                as1[row * 4 + wv] = a_;
                ad1[row * 4 + wv] = d_;
            }
        }
    }
}

// ---------------- layer 1 aggregation (fp8 messages, fused edge weights) --
// Round-3-verified structure (43.6-43.7us across r7/r8 = measured floor:
// FETCH ~95MB compulsory L2 fill @ ~2.2TB/s, VALU co-busy 72%). FROZEN —
// r4 (16-lane groups), r6 (head-sliced XCD), r8 (packed FMA: neutral) all
// failed to beat it.
__global__ __launch_bounds__(256) void k_agg1(const unsigned char* __restrict__ h1f8,
                                              const float* __restrict__ as1,
                                              const float* __restrict__ ad1,
                                              const int* __restrict__ offs,
                                              const int* __restrict__ ssrc,
                                              const float* __restrict__ b1,
                                              unsigned short* __restrict__ g1b) {
    int lane = threadIdx.x & 63;
    int half = lane >> 5;
    int hl = lane & 31;          // channel group: ch hl*8..+7
    int head = hl >> 3;
    int node = blockIdx.x * 4 + (threadIdx.x >> 6);
    int beg = offs[node];
    int end = (node + 1 < NN) ? offs[node + 1] : NE;
    float adv = ad1[node * 4 + head];
    float l = 0.f;
    f32x2 acc2[4];
#pragma unroll
    for (int c = 0; c < 4; c++) acc2[c] = (f32x2){0.f, 0.f};
    const uint2* hv = (const uint2*)h1f8;   // 32 uint2 per row

#define ACC1(hb, p)                                                                   \
    {                                                                                 \
        f32x2 pp = {(p), (p)};                                                        \
        acc2[0] = __builtin_elementwise_fma(                                          \
            pp, __builtin_amdgcn_cvt_pk_f32_fp8((hb).x, false), acc2[0]);             \
        acc2[1] = __builtin_elementwise_fma(                                          \
            pp, __builtin_amdgcn_cvt_pk_f32_fp8((hb).x, true), acc2[1]);              \
        acc2[2] = __builtin_elementwise_fma(                                          \
            pp, __builtin_amdgcn_cvt_pk_f32_fp8((hb).y, false), acc2[2]);             \
        acc2[3] = __builtin_elementwise_fma(                                          \
            pp, __builtin_amdgcn_cvt_pk_f32_fp8((hb).y, true), acc2[3]);              \
        l += (p);                                                                     \
    }

    if (beg < end) {
        int idx[4];
#pragma unroll
        for (int i = 0; i < 4; i++) idx[i] = ssrc[beg + 2 * i + half];
        uint2 hbA[2];
        float pA[2];
#pragma unroll
        for (int i = 0; i < 2; i++) {
            hbA[i] = hv[(size_t)idx[i] * 32 + hl];
            int e = beg + 2 * i + half;
            float p = __expf(lrelu(as1[idx[i] * 4 + head] + adv));
            pA[i] = (e < end) ? p : 0.f;
        }
        for (int j = beg; j < end; j += 8) {
            int idxN[4];
#pragma unroll
            for (int i = 0; i < 4; i++) idxN[i] = ssrc[j + 8 + 2 * i + half];
            uint2 hbB[2];
            float pB[2];
#pragma unroll
            for (int i = 0; i < 2; i++) {
                hbB[i] = hv[(size_t)idx[2 + i] * 32 + hl];
                int e = j + 4 + 2 * i + half;
                float p = __expf(lrelu(as1[idx[2 + i] * 4 + head] + adv));
                pB[i] = (e < end) ? p : 0.f;
            }
            ACC1(hbA[0], pA[0]);
            ACC1(hbA[1], pA[1]);
#pragma unroll
            for (int i = 0; i < 2; i++) {
                hbA[i] = hv[(size_t)idxN[i] * 32 + hl];
                int e = j + 8 + 2 * i + half;
                float p = __expf(lrelu(as1[idxN[i] * 4 + head] + adv));
                pA[i] = (e < end) ? p : 0.f;
            }
            ACC1(hbB[0], pB[0]);
            ACC1(hbB[1], pB[1]);
#pragma unroll
            for (int i = 0; i < 4; i++) idx[i] = idxN[i];
        }
    }
#undef ACC1
    // combine the two halves (same channels, disjoint edge subsets)
    l += __shfl_xor(l, 32);
#pragma unroll
    for (int c = 0; c < 4; c++) {
        acc2[c][0] += __shfl_xor(acc2[c][0], 32);
        acc2[c][1] += __shfl_xor(acc2[c][1], 32);
    }

    if (half == 0) {
        float inv = 1.f / (l + EPSF);
        const float4* b1v = (const float4*)b1;
        float4 b0 = b1v[hl * 2];
        float4 b1_ = b1v[hl * 2 + 1];
        float o[8];
        o[0] = fmaxf(fmaf(acc2[0][0], inv, b0.x), 0.f);
        o[1] = fmaxf(fmaf(acc2[0][1], inv, b0.y), 0.f);
        o[2] = fmaxf(fmaf(acc2[1][0], inv, b0.z), 0.f);
        o[3] = fmaxf(fmaf(acc2[1][1], inv, b0.w), 0.f);
        o[4] = fmaxf(fmaf(acc2[2][0], inv, b1_.x), 0.f);
        o[5] = fmaxf(fmaf(acc2[2][1], inv, b1_.y), 0.f);
        o[6] = fmaxf(fmaf(acc2[3][0], inv, b1_.z), 0.f);
        o[7] = fmaxf(fmaf(acc2[3][1], inv, b1_.w), 0.f);
        uint4 ob;
        ob.x = (unsigned int)f2bf(o[0]) | ((unsigned int)f2bf(o[1]) << 16);
        ob.y = (unsigned int)f2bf(o[2]) | ((unsigned int)f2bf(o[3]) << 16);
        ob.z = (unsigned int)f2bf(o[4]) | ((unsigned int)f2bf(o[5]) << 16);
        ob.w = (unsigned int)f2bf(o[6]) | ((unsigned int)f2bf(o[7]) << 16);
        ((uint4*)g1b)[(size_t)node * 32 + hl] = ob;
    }
}

// ---------------- layer 2: bf16 MFMA GEMM + fused alpha2 -----------------
__global__ __launch_bounds__(256) void k_gemm2(const unsigned short* __restrict__ g1b,
                                               const unsigned short* __restrict__ wB2,
                                               const float* __restrict__ aws,
                                               const float* __restrict__ awd,
                                               unsigned short* __restrict__ h2b,
                                               float* __restrict__ as2,
                                               float* __restrict__ ad2) {
    __shared__ uint4 Af[4][8][64];   // [mt][kc][lane], 32 KB
    int t = threadIdx.x;
    int m0 = blockIdx.x * 64;

#pragma unroll
    for (int i = 0; i < 8; i++) {
        int g = i * 256 + t;
        int row = g >> 5;
        int c8 = g & 31;
        int grow = m0 + row;
        if (grow >= NN) grow = NN - 1;
        uint4 v = *(const uint4*)(g1b + (size_t)grow * C1 + c8 * 8);
        int kc = c8 >> 2;
        int q = c8 & 3;
        Af[row >> 4][kc][q * 16 + (row & 15)] = v;
    }
    __syncthreads();

    int l = t & 63;
    int wv = t >> 6;

    bf16x8 a[8];
#pragma unroll
    for (int kc = 0; kc < 8; kc++) a[kc] = *(const bf16x8*)&Af[wv][kc][l];

    f32x4 acc[3];
#pragma unroll
    for (int tn = 0; tn < 3; tn++) acc[tn] = (f32x4){0.f, 0.f, 0.f, 0.f};

    const bf16x8* wb = (const bf16x8*)wB2 + l;
#pragma unroll
    for (int tn = 0; tn < 3; tn++) {
#pragma unroll
        for (int kc = 0; kc < 8; kc++) {
            bf16x8 b = wb[(tn * 8 + kc) * 64];
            acc[tn] = __builtin_amdgcn_mfma_f32_16x16x32_bf16(a[kc], b, acc[tn], 0, 0, 0);
        }
    }

    int q = l >> 4;
    int c = l & 15;
    int row0 = m0 + wv * 16 + q * 4;
    float ps[4] = {0.f, 0.f, 0.f, 0.f}, pd[4] = {0.f, 0.f, 0.f, 0.f};
#pragma unroll
    for (int tn = 0; tn < 3; tn++) {
        int col = tn * 16 + c;
        bool cok = col < CLS;
        float wsv = cok ? aws[col] : 0.f;
        float wdv = cok ? awd[col] : 0.f;
#pragma unroll
        for (int r = 0; r < 4; r++) {
            float v = acc[tn][r];
            int row = row0 + r;
            if (cok && row < NN) h2b[(size_t)row * CLS + col] = f2bf(v);
            ps[r] = fmaf(v, wsv, ps[r]);
            pd[r] = fmaf(v, wdv, pd[r]);
        }
    }
#pragma unroll
    for (int r = 0; r < 4; r++) {
        float a_ = ps[r], d_ = pd[r];
#pragma unroll
        for (int s = 1; s < 16; s <<= 1) {
            a_ += __shfl_xor(a_, s);
            d_ += __shfl_xor(d_, s);
        }
        int row = row0 + r;
        if (c == 0 && row < NN) {
            as2[row] = a_;
            ad2[row] = d_;
        }
    }
}

// ---------------- layer 2 aggregation + fused log_softmax ----------------
// Deepened prefetch: 16-edge window, 4 gathers in flight per half (was 8/2).
// agg2 has little VALU per edge (1 pk-fma per uint) so the gather latency
// was poorly hidden; more MLP at zero occupancy cost (VGPR 32 -> ~48).
__global__ __launch_bounds__(256) void k_agg2(const unsigned short* __restrict__ h2b,
                                              const float* __restrict__ as2,
                                              const float* __restrict__ ad2,
                                              const int* __restrict__ offs,
                                              const int* __restrict__ ssrc,
                                              const float* __restrict__ b2,
                                              float* __restrict__ out) {
    int lane = threadIdx.x & 63;
    int half = lane >> 5;
    int hl = lane & 31;
    int cl = hl < 20 ? hl : 19;   // uint index within row (2 channels)
    int node = blockIdx.x * 4 + (threadIdx.x >> 6);
    int beg = offs[node];
    int end = (node + 1 < NN) ? offs[node + 1] : NE;
    float adv = ad2[node];
    float l = 0.f;
    f32x2 acc = {0.f, 0.f};
    const unsigned int* hv = (const unsigned int*)h2b;   // 20 uints per row

#define ACC2(hb, p)                                                        \
    {                                                                      \
        f32x2 pp = {(p), (p)};                                             \
        f32x2 bf = {bflo(hb), bfhi(hb)};                                   \
        acc = __builtin_elementwise_fma(pp, bf, acc);                      \
        l += (p);                                                          \
    }

    if (beg < end) {
        int idx[8];
#pragma unroll
        for (int i = 0; i < 8; i++) idx[i] = ssrc[beg + 2 * i + half];
        unsigned int hbA[4];
        float pA[4];
#pragma unroll
        for (int i = 0; i < 4; i++) {
            hbA[i] = hv[(size_t)idx[i] * 20 + cl];
            int e = beg + 2 * i + half;
            float p = __expf(lrelu(as2[idx[i]] + adv));
            pA[i] = (e < end) ? p : 0.f;
        }
        for (int j = beg; j < end; j += 16) {
            int idxN[8];
#pragma unroll
            for (int i = 0; i < 8; i++) idxN[i] = ssrc[j + 16 + 2 * i + half];
            unsigned int hbB[4];
            float pB[4];
#pragma unroll
            for (int i = 0; i < 4; i++) {
                hbB[i] = hv[(size_t)idx[4 + i] * 20 + cl];
                int e = j + 8 + 2 * i + half;
                float p = __expf(lrelu(as2[idx[4 + i]] + adv));
                pB[i] = (e < end) ? p : 0.f;
            }
            ACC2(hbA[0], pA[0]);
            ACC2(hbA[1], pA[1]);
            ACC2(hbA[2], pA[2]);
            ACC2(hbA[3], pA[3]);
#pragma unroll
            for (int i = 0; i < 4; i++) {
                hbA[i] = hv[(size_t)idxN[i] * 20 + cl];
                int e = j + 16 + 2 * i + half;
                float p = __expf(lrelu(as2[idxN[i]] + adv));
                pA[i] = (e < end) ? p : 0.f;
            }
            ACC2(hbB[0], pB[0]);
            ACC2(hbB[1], pB[1]);
            ACC2(hbB[2], pB[2]);
            ACC2(hbB[3], pB[3]);
#pragma unroll
            for (int i = 0; i < 8; i++) idx[i] = idxN[i];
        }
    }
#undef ACC2
    l += __shfl_xor(l, 32);
    acc[0] += __shfl_xor(acc[0], 32);
    acc[1] += __shfl_xor(acc[1], 32);

    if (half == 0) {
        bool act = hl < 20;
        float inv = 1.f / (l + EPSF);
        float vL = -INFINITY, vH = -INFINITY;
        if (act) {
            float2 b = ((const float2*)b2)[cl];
            vL = acc[0] * inv + b.x;
            vH = acc[1] * inv + b.y;
        }
        float mx = fmaxf(vL, vH);
#pragma unroll
        for (int s = 16; s >= 1; s >>= 1) mx = fmaxf(mx, __shfl_xor(mx, s));
        float ex = act ? (__expf(vL - mx) + __expf(vH - mx)) : 0.f;
#pragma unroll
        for (int s = 16; s >= 1; s >>= 1) ex += __shfl_xor(ex, s);
        if (act) {
            float ls = __logf(ex);
            float2 o = {vL - mx - ls, vH - mx - ls};
            *(float2*)(out + (size_t)node * CLS + cl * 2) = o;
        }
    }
}

// ---------------- launch ----------------

extern "C" void kernel_launch(void* const* d_in, const int* in_sizes, int n_in,
                              void* d_out, int out_size, void* d_ws, size_t ws_size,
                              hipStream_t stream) {
    const float* x    = (const float*)d_in[0];
    const int*   ei   = (const int*)d_in[1];
    const float* W1   = (const float*)d_in[2];
    const float* as1w = (const float*)d_in[3];
    const float* ad1w = (const float*)d_in[4];
    const float* b1   = (const float*)d_in[5];
    const float* W2   = (const float*)d_in[6];
    const float* as2w = (const float*)d_in[7];
    const float* ad2w = (const float*)d_in[8];
    const float* b2   = (const float*)d_in[9];
    float* out = (float*)d_out;

    char* p = (char*)d_ws;
    auto alloc = [&](size_t bytes) {
        char* r = p;
        p += (bytes + 255) & ~(size_t)255;
        return r;
    };
    unsigned char* h1f8 = (unsigned char*)alloc((size_t)NN * C1);
    unsigned short* g1b = (unsigned short*)alloc((size_t)NN * C1 * 2);
    unsigned short* h2b = (unsigned short*)alloc((size_t)NN * CLS * 2);
    float* as1  = (float*)alloc((size_t)NN * 4 * 4);
    float* ad1  = (float*)alloc((size_t)NN * 4 * 4);
    float* as2  = (float*)alloc((size_t)NN * 4);
    float* ad2  = (float*)alloc((size_t)NN * 4);
    int* offs   = (int*)alloc((size_t)(NN + 1024) * 4);  // +pad: bsg writes 98*512 entries
    int* gcur   = (int*)alloc(128 * 4);
    unsigned int* stage = (unsigned int*)alloc((size_t)NB * BSTRIDE * 4);
    int* ssrc   = (int*)alloc((size_t)(NE + 64) * 4);
    unsigned short* wB1 = (unsigned short*)alloc((size_t)4096 * 8 * 2);
    unsigned short* wB2 = (unsigned short*)alloc((size_t)1536 * 8 * 2);

    hipMemsetAsync(gcur, 0, 128 * 4, stream);

    k_bucket<<<NBLK_B, 512, 0, stream>>>(ei, gcur, stage, W1, W2, wB1, wB2, ssrc + NE);
    k_bsg<<<NB + NBLK_G, 512, 0, stream>>>(stage, gcur, offs, ssrc,
                                           x, wB1, as1w, ad1w, h1f8, as1, ad1);
    k_agg1<<<NN / 4, 256, 0, stream>>>(h1f8, as1, ad1, offs, ssrc, b1, g1b);

    k_gemm2<<<(NN + 63) / 64, 256, 0, stream>>>(g1b, wB2, as2w, ad2w, h2b, as2, ad2);
    k_agg2<<<NN / 4, 256, 0, stream>>>(h2b, as2, ad2, offs, ssrc, b2, out);
}

// Round 10
// 196.555 us; speedup vs baseline: 1.0621x; 1.0621x over previous
//
#include <hip/hip_runtime.h>
#include <math.h>

#define NN 50000
#define NE 800000
#define FIN 128
#define HID 64
#define HEADS 4
#define C1 256   // HEADS*HID
#define CLS 40
#define EPSF 1e-16f

// bucket sort params: 98 buckets of 512 dst nodes each
#define NB 98
#define BSH 9
#define BSTRIDE 9216     // > max bucket count (mean 8192, +11 sigma), 64B-aligned
#define NBLK_B 625
#define CHUNK 1280       // 625*1280 == NE exactly. r9 tried 640 (2x blocks):
                         // REGRESSED ~+13us total — halving run length fragments
                         // the stage write-out (write-locality >> block latency).
#define NBLK_G 391       // ceil(50000/128) gemm1 double-tiles

typedef __attribute__((ext_vector_type(8))) short bf16x8;
typedef __attribute__((ext_vector_type(4))) float f32x4;
typedef __attribute__((ext_vector_type(2))) float f32x2;

__device__ __forceinline__ unsigned short f2bf(float f) {
    unsigned int u = __float_as_uint(f);
    unsigned int r = (u + 0x7fffu + ((u >> 16) & 1u)) >> 16;   // RNE
    return (unsigned short)r;
}
__device__ __forceinline__ float bflo(unsigned int u) { return __uint_as_float(u << 16); }
__device__ __forceinline__ float bfhi(unsigned int u) { return __uint_as_float(u & 0xffff0000u); }
__device__ __forceinline__ unsigned char f2fp8(float v) {
    int pk = __builtin_amdgcn_cvt_pk_fp8_f32(v, v, 0, false);
    return (unsigned char)(pk & 0xff);
}
__device__ __forceinline__ float lrelu(float e) { return e > 0.f ? e : 0.2f * e; }

// ---------------- two-level bucket sort of edges by dst ----------------
// Level 1: partition edges into 98 coarse buckets; in-LDS counting sort by
// bucket before the global write so stage writes are coalesced line bursts.
// Blocks 0..10 additionally perform the one-time W1/W2 -> MFMA-fragment
// conversion; block 0 also zeroes the ssrc tail pad (replaces a memset).
__global__ __launch_bounds__(512) void k_bucket(const int* __restrict__ ei,
                                                int* __restrict__ gcur,
                                                unsigned int* __restrict__ stage,
                                                const float* __restrict__ W1,
                                                const float* __restrict__ W2,
                                                unsigned short* __restrict__ wB1,
                                                unsigned short* __restrict__ wB2,
                                                int* __restrict__ ssrc_pad) {
    __shared__ unsigned int lchunk[CHUNK];
    __shared__ unsigned int lsort[CHUNK];
    __shared__ int lhist[128];
    __shared__ int sbuf[128];
    __shared__ int lstart[128];
    __shared__ int lbase[128];
    __shared__ int lcur[128];
    int t = threadIdx.x;

    // folded-in weight conversion (independent work, overlaps LDS phase)
    if (blockIdx.x < 11) {
        int tw = blockIdx.x * 512 + t;
        if (blockIdx.x == 0 && t >= 448) ssrc_pad[t - 448] = 0;  // ssrc[NE..NE+63]
        if (tw < 4096) {
            int tn = tw >> 8;
            int kc = (tw >> 6) & 3;
            int lw = tw & 63;
            int n = tn * 16 + (lw & 15);
            int k0 = kc * 32 + (lw >> 4) * 8;
            unsigned short* o = wB1 + (size_t)tw * 8;
#pragma unroll
            for (int j = 0; j < 8; j++) o[j] = f2bf(W1[(size_t)(k0 + j) * C1 + n]);
        } else if (tw < 4096 + 1536) {
            int u = tw - 4096;
            int tn = u >> 9;
            int kc = (u >> 6) & 7;
            int lw = u & 63;
            int n = tn * 16 + (lw & 15);
            int k0 = kc * 32 + (lw >> 4) * 8;
            unsigned short* o = wB2 + (size_t)u * 8;
#pragma unroll
            for (int j = 0; j < 8; j++)
                o[j] = (n < CLS) ? f2bf(W2[(size_t)(k0 + j) * CLS + n]) : (unsigned short)0;
        }
    }

    int e0 = blockIdx.x * CHUNK;
    if (t < 128) lhist[t] = 0;
    __syncthreads();
    for (int j = t; j < CHUNK; j += 512) {
        int s = ei[e0 + j];
        int d = ei[NE + e0 + j];
        int b = d >> BSH;
        atomicAdd(&lhist[b], 1);
        lchunk[j] = (unsigned int)s | ((unsigned int)(d & 511) << 16) |
                    ((unsigned int)b << 25);
    }
    __syncthreads();
    // exclusive scan of the 128 bins (Hillis-Steele in LDS)
    if (t < 128) sbuf[t] = lhist[t];
    __syncthreads();
    for (int d = 1; d < 128; d <<= 1) {
        int x = (t < 128 && t >= d) ? sbuf[t - d] : 0;
        __syncthreads();
        if (t < 128) sbuf[t] += x;
        __syncthreads();
    }
    if (t < 128) {
        int excl = sbuf[t] - lhist[t];
        lstart[t] = excl;
        lcur[t] = excl;
        if (t < NB) lbase[t] = atomicAdd(&gcur[t], lhist[t]);
    }
    __syncthreads();
    // in-LDS counting sort by bucket
    for (int j = t; j < CHUNK; j += 512) {
        unsigned int pk = lchunk[j];
        int b = pk >> 25;
        int pos = atomicAdd(&lcur[b], 1);
        lsort[pos] = pk;
    }
    __syncthreads();
    // coalesced write-out: consecutive j -> consecutive dest within a run
    for (int j = t; j < CHUNK; j += 512) {
        unsigned int pk = lsort[j];
        int b = pk >> 25;
        int dest = lbase[b] + (j - lstart[b]);
        stage[(size_t)b * BSTRIDE + dest] = pk & 0x01FFFFFFu;
    }
}

// ---------------- fused bsort + gemm1 (independent work, one dispatch) ----
// Blocks 0..NB-1: per-bucket LDS counting sort (bsort body, 512 threads).
// Blocks NB..NB+390: TWO copies of the verified 256-thread gemm1 tile.
__global__ __launch_bounds__(512) void k_bsg(const unsigned int* __restrict__ stage,
                                             const int* __restrict__ gcur,
                                             int* __restrict__ offs,
                                             int* __restrict__ ssrc,
                                             const float* __restrict__ x,
                                             const unsigned short* __restrict__ wB,
                                             const float* __restrict__ aws,
                                             const float* __restrict__ awd,
                                             unsigned char* __restrict__ h1f8,
                                             float* __restrict__ as1,
                                             float* __restrict__ ad1) {
    __shared__ union SM {
        struct { int lhist[512]; int cur[512]; int sbuf[128]; } b;
        struct { uint4 Af[2][4][4][64]; } g;   // 32 KB
    } sm;

    if (blockIdx.x < NB) {
        // ---------------- bsort body ----------------
        int t = threadIdx.x;
        int b = blockIdx.x;
        int cnt = gcur[b];
        const unsigned int* sp = stage + (size_t)b * BSTRIDE;
        if (t < 128) sm.b.sbuf[t] = (t < NB) ? gcur[t] : 0;
        sm.b.lhist[t] = 0;
        __syncthreads();
        for (int d = 1; d < 128; d <<= 1) {
            int xv = (t < 128 && t >= d) ? sm.b.sbuf[t - d] : 0;
            __syncthreads();
            if (t < 128) sm.b.sbuf[t] += xv;
            __syncthreads();
        }
        int gbase = sm.b.sbuf[b] - cnt;
        for (int j = t; j < cnt; j += 512) atomicAdd(&sm.b.lhist[(sp[j] >> 16) & 511], 1);
        __syncthreads();
        if (t < 64) {
            int base = t * 8;
            int vals[8];
            int run = 0;
#pragma unroll
            for (int j = 0; j < 8; j++) { int v = sm.b.lhist[base + j]; vals[j] = run; run += v; }
            int sc = run;
#pragma unroll
            for (int d = 1; d < 64; d <<= 1) { int u = __shfl_up(sc, d); if (t >= d) sc += u; }
            int excl = sc - run;
#pragma unroll
            for (int j = 0; j < 8; j++) sm.b.cur[base + j] = excl + vals[j];
        }
        __syncthreads();
        offs[(b << BSH) + t] = gbase + sm.b.cur[t];
        __syncthreads();
        for (int j = t; j < cnt; j += 512) {
            unsigned int v = sp[j];
            int dl = (v >> 16) & 511;
            int pos = atomicAdd(&sm.b.cur[dl], 1);
            ssrc[gbase + pos] = (int)(v & 0xFFFFu);
        }
        return;
    }

    // ---------------- gemm1 body (two 64-row tiles per block) ----------------
    int half = threadIdx.x >> 8;
    int t = threadIdx.x & 255;
    int m0 = ((blockIdx.x - NB) * 2 + half) * 64;
    int l = t & 63;
    int wv = t >> 6;                 // wave-quarter within the half = head

    // prefetch the wave's 16 B-fragments (independent; overlap staging)
    bf16x8 bf[4][4];
    const bf16x8* wb = (const bf16x8*)wB + l;
#pragma unroll
    for (int tn = 0; tn < 4; tn++)
#pragma unroll
        for (int kc = 0; kc < 4; kc++)
            bf[tn][kc] = wb[(((wv * 4 + tn) * 4 + kc)) * 64];

#pragma unroll
    for (int i = 0; i < 8; i++) {
        int g = i * 256 + t;
        int row = g >> 5;
        int c4 = g & 31;
        int grow = m0 + row;
        if (grow >= NN) grow = NN - 1;
        float4 v = *(const float4*)(x + (size_t)grow * FIN + c4 * 4);
        uint2 pk;
        pk.x = (unsigned int)f2bf(v.x) | ((unsigned int)f2bf(v.y) << 16);
        pk.y = (unsigned int)f2bf(v.z) | ((unsigned int)f2bf(v.w) << 16);
        int kc = c4 >> 3;
        int rem = (c4 & 7) * 4;
        int q = rem >> 3;
        int hh = (rem >> 2) & 1;
        int ll = q * 16 + (row & 15);
        int mt = row >> 4;
        ((uint2*)&sm.g.Af[half][mt][kc][ll])[hh] = pk;
    }
    __syncthreads();

    int q = l >> 4;
    int c = l & 15;

#pragma unroll
    for (int mt = 0; mt < 4; mt++) {
        bf16x8 a[4];
#pragma unroll
        for (int kc = 0; kc < 4; kc++) a[kc] = *(const bf16x8*)&sm.g.Af[half][mt][kc][l];

        f32x4 acc[4];
#pragma unroll
        for (int tn = 0; tn < 4; tn++) acc[tn] = (f32x4){0.f, 0.f, 0.f, 0.f};
#pragma unroll
        for (int tn = 0; tn < 4; tn++) {
            acc[tn] = __builtin_amdgcn_mfma_f32_16x16x32_bf16(a[0], bf[tn][0], acc[tn], 0, 0, 0);
            acc[tn] = __builtin_amdgcn_mfma_f32_16x16x32_bf16(a[1], bf[tn][1], acc[tn], 0, 0, 0);
            acc[tn] = __builtin_amdgcn_mfma_f32_16x16x32_bf16(a[2], bf[tn][2], acc[tn], 0, 0, 0);
            acc[tn] = __builtin_amdgcn_mfma_f32_16x16x32_bf16(a[3], bf[tn][3], acc[tn], 0, 0, 0);
        }

        int row0 = m0 + mt * 16 + q * 4;
        float ps[4] = {0.f, 0.f, 0.f, 0.f}, pd[4] = {0.f, 0.f, 0.f, 0.f};
#pragma unroll
        for (int tn = 0; tn < 4; tn++) {
            int col = wv * 64 + tn * 16 + c;
            float wsv = aws[col];
            float wdv = awd[col];
#pragma unroll
            for (int r = 0; r < 4; r++) {
                float v = acc[tn][r];
                int row = row0 + r;
                if (row < NN) h1f8[(size_t)row * C1 + col] = f2fp8(v);
                ps[r] = fmaf(v, wsv, ps[r]);
                pd[r] = fmaf(v, wdv, pd[r]);
            }
        }
#pragma unroll
        for (int r = 0; r < 4; r++) {
            float a_ = ps[r], d_ = pd[r];
#pragma unroll
            for (int s = 1; s < 16; s <<= 1) {
                a_ += __shfl_xor(a_, s);
                d_ += __shfl_xor(d_, s);
            }
            int row = row0 + r;
            if (c == 0 && row < NN) {
                as1[row * 4 + wv] = a_;
                ad1[row * 4 + wv] = d_;
            }
        }
    }
}

// ---------------- layer 1 aggregation (fp8 messages, fused edge weights) --
// Round-3-verified structure (43.6-43.7us across r7/r8 = measured floor:
// FETCH ~95MB compulsory L2 fill @ ~2.2TB/s, VALU co-busy 72%). FROZEN —
// r4 (16-lane groups), r6 (head-sliced XCD), r8 (packed FMA: neutral) all
// failed to beat it.
__global__ __launch_bounds__(256) void k_agg1(const unsigned char* __restrict__ h1f8,
                                              const float* __restrict__ as1,
                                              const float* __restrict__ ad1,
                                              const int* __restrict__ offs,
                                              const int* __restrict__ ssrc,
                                              const float* __restrict__ b1,
                                              unsigned short* __restrict__ g1b) {
    int lane = threadIdx.x & 63;
    int half = lane >> 5;
    int hl = lane & 31;          // channel group: ch hl*8..+7
    int head = hl >> 3;
    int node = blockIdx.x * 4 + (threadIdx.x >> 6);
    int beg = offs[node];
    int end = (node + 1 < NN) ? offs[node + 1] : NE;
    float adv = ad1[node * 4 + head];
    float l = 0.f;
    f32x2 acc2[4];
#pragma unroll
    for (int c = 0; c < 4; c++) acc2[c] = (f32x2){0.f, 0.f};
    const uint2* hv = (const uint2*)h1f8;   // 32 uint2 per row

#define ACC1(hb, p)                                                                   \
    {                                                                                 \
        f32x2 pp = {(p), (p)};                                                        \
        acc2[0] = __builtin_elementwise_fma(                                          \
            pp, __builtin_amdgcn_cvt_pk_f32_fp8((hb).x, false), acc2[0]);             \
        acc2[1] = __builtin_elementwise_fma(                                          \
            pp, __builtin_amdgcn_cvt_pk_f32_fp8((hb).x, true), acc2[1]);              \
        acc2[2] = __builtin_elementwise_fma(                                          \
            pp, __builtin_amdgcn_cvt_pk_f32_fp8((hb).y, false), acc2[2]);             \
        acc2[3] = __builtin_elementwise_fma(                                          \
            pp, __builtin_amdgcn_cvt_pk_f32_fp8((hb).y, true), acc2[3]);              \
        l += (p);                                                                     \
    }

    if (beg < end) {
        int idx[4];
#pragma unroll
        for (int i = 0; i < 4; i++) idx[i] = ssrc[beg + 2 * i + half];
        uint2 hbA[2];
        float pA[2];
#pragma unroll
        for (int i = 0; i < 2; i++) {
            hbA[i] = hv[(size_t)idx[i] * 32 + hl];
            int e = beg + 2 * i + half;
            float p = __expf(lrelu(as1[idx[i] * 4 + head] + adv));
            pA[i] = (e < end) ? p : 0.f;
        }
        for (int j = beg; j < end; j += 8) {
            int idxN[4];
#pragma unroll
            for (int i = 0; i < 4; i++) idxN[i] = ssrc[j + 8 + 2 * i + half];
            uint2 hbB[2];
            float pB[2];
#pragma unroll
            for (int i = 0; i < 2; i++) {
                hbB[i] = hv[(size_t)idx[2 + i] * 32 + hl];
                int e = j + 4 + 2 * i + half;
                float p = __expf(lrelu(as1[idx[2 + i] * 4 + head] + adv));
                pB[i] = (e < end) ? p : 0.f;
            }
            ACC1(hbA[0], pA[0]);
            ACC1(hbA[1], pA[1]);
#pragma unroll
            for (int i = 0; i < 2; i++) {
                hbA[i] = hv[(size_t)idxN[i] * 32 + hl];
                int e = j + 8 + 2 * i + half;
                float p = __expf(lrelu(as1[idxN[i] * 4 + head] + adv));
                pA[i] = (e < end) ? p : 0.f;
            }
            ACC1(hbB[0], pB[0]);
            ACC1(hbB[1], pB[1]);
#pragma unroll
            for (int i = 0; i < 4; i++) idx[i] = idxN[i];
        }
    }
#undef ACC1
    // combine the two halves (same channels, disjoint edge subsets)
    l += __shfl_xor(l, 32);
#pragma unroll
    for (int c = 0; c < 4; c++) {
        acc2[c][0] += __shfl_xor(acc2[c][0], 32);
        acc2[c][1] += __shfl_xor(acc2[c][1], 32);
    }

    if (half == 0) {
        float inv = 1.f / (l + EPSF);
        const float4* b1v = (const float4*)b1;
        float4 b0 = b1v[hl * 2];
        float4 b1_ = b1v[hl * 2 + 1];
        float o[8];
        o[0] = fmaxf(fmaf(acc2[0][0], inv, b0.x), 0.f);
        o[1] = fmaxf(fmaf(acc2[0][1], inv, b0.y), 0.f);
        o[2] = fmaxf(fmaf(acc2[1][0], inv, b0.z), 0.f);
        o[3] = fmaxf(fmaf(acc2[1][1], inv, b0.w), 0.f);
        o[4] = fmaxf(fmaf(acc2[2][0], inv, b1_.x), 0.f);
        o[5] = fmaxf(fmaf(acc2[2][1], inv, b1_.y), 0.f);
        o[6] = fmaxf(fmaf(acc2[3][0], inv, b1_.z), 0.f);
        o[7] = fmaxf(fmaf(acc2[3][1], inv, b1_.w), 0.f);
        uint4 ob;
        ob.x = (unsigned int)f2bf(o[0]) | ((unsigned int)f2bf(o[1]) << 16);
        ob.y = (unsigned int)f2bf(o[2]) | ((unsigned int)f2bf(o[3]) << 16);
        ob.z = (unsigned int)f2bf(o[4]) | ((unsigned int)f2bf(o[5]) << 16);
        ob.w = (unsigned int)f2bf(o[6]) | ((unsigned int)f2bf(o[7]) << 16);
        ((uint4*)g1b)[(size_t)node * 32 + hl] = ob;
    }
}

// ---------------- layer 2: bf16 MFMA GEMM + fused alpha2 -----------------
__global__ __launch_bounds__(256) void k_gemm2(const unsigned short* __restrict__ g1b,
                                               const unsigned short* __restrict__ wB2,
                                               const float* __restrict__ aws,
                                               const float* __restrict__ awd,
                                               unsigned short* __restrict__ h2b,
                                               float* __restrict__ as2,
                                               float* __restrict__ ad2) {
    __shared__ uint4 Af[4][8][64];   // [mt][kc][lane], 32 KB
    int t = threadIdx.x;
    int m0 = blockIdx.x * 64;

#pragma unroll
    for (int i = 0; i < 8; i++) {
        int g = i * 256 + t;
        int row = g >> 5;
        int c8 = g & 31;
        int grow = m0 + row;
        if (grow >= NN) grow = NN - 1;
        uint4 v = *(const uint4*)(g1b + (size_t)grow * C1 + c8 * 8);
        int kc = c8 >> 2;
        int q = c8 & 3;
        Af[row >> 4][kc][q * 16 + (row & 15)] = v;
    }
    __syncthreads();

    int l = t & 63;
    int wv = t >> 6;

    bf16x8 a[8];
#pragma unroll
    for (int kc = 0; kc < 8; kc++) a[kc] = *(const bf16x8*)&Af[wv][kc][l];

    f32x4 acc[3];
#pragma unroll
    for (int tn = 0; tn < 3; tn++) acc[tn] = (f32x4){0.f, 0.f, 0.f, 0.f};

    const bf16x8* wb = (const bf16x8*)wB2 + l;
#pragma unroll
    for (int tn = 0; tn < 3; tn++) {
#pragma unroll
        for (int kc = 0; kc < 8; kc++) {
            bf16x8 b = wb[(tn * 8 + kc) * 64];
            acc[tn] = __builtin_amdgcn_mfma_f32_16x16x32_bf16(a[kc], b, acc[tn], 0, 0, 0);
        }
    }

    int q = l >> 4;
    int c = l & 15;
    int row0 = m0 + wv * 16 + q * 4;
    float ps[4] = {0.f, 0.f, 0.f, 0.f}, pd[4] = {0.f, 0.f, 0.f, 0.f};
#pragma unroll
    for (int tn = 0; tn < 3; tn++) {
        int col = tn * 16 + c;
        bool cok = col < CLS;
        float wsv = cok ? aws[col] : 0.f;
        float wdv = cok ? awd[col] : 0.f;
#pragma unroll
        for (int r = 0; r < 4; r++) {
            float v = acc[tn][r];
            int row = row0 + r;
            if (cok && row < NN) h2b[(size_t)row * CLS + col] = f2bf(v);
            ps[r] = fmaf(v, wsv, ps[r]);
            pd[r] = fmaf(v, wdv, pd[r]);
        }
    }
#pragma unroll
    for (int r = 0; r < 4; r++) {
        float a_ = ps[r], d_ = pd[r];
#pragma unroll
        for (int s = 1; s < 16; s <<= 1) {
            a_ += __shfl_xor(a_, s);
            d_ += __shfl_xor(d_, s);
        }
        int row = row0 + r;
        if (c == 0 && row < NN) {
            as2[row] = a_;
            ad2[row] = d_;
        }
    }
}

// ---------------- layer 2 aggregation + fused log_softmax ----------------
// Round-3-verified structure; {bflo,bfhi} packed into one f32x2 FMA.
// r9 tried a 16-edge window: REGRESSED — mean degree is 16, so the wider
// window wastes ~8 masked gathers/node-half (issued traffic, p=0).
__global__ __launch_bounds__(256) void k_agg2(const unsigned short* __restrict__ h2b,
                                              const float* __restrict__ as2,
                                              const float* __restrict__ ad2,
                                              const int* __restrict__ offs,
                                              const int* __restrict__ ssrc,
                                              const float* __restrict__ b2,
                                              float* __restrict__ out) {
    int lane = threadIdx.x & 63;
    int half = lane >> 5;
    int hl = lane & 31;
    int cl = hl < 20 ? hl : 19;   // uint index within row (2 channels)
    int node = blockIdx.x * 4 + (threadIdx.x >> 6);
    int beg = offs[node];
    int end = (node + 1 < NN) ? offs[node + 1] : NE;
    float adv = ad2[node];
    float l = 0.f;
    f32x2 acc = {0.f, 0.f};
    const unsigned int* hv = (const unsigned int*)h2b;   // 20 uints per row

#define ACC2(hb, p)                                                        \
    {                                                                      \
        f32x2 pp = {(p), (p)};                                             \
        f32x2 bf = {bflo(hb), bfhi(hb)};                                   \
        acc = __builtin_elementwise_fma(pp, bf, acc);                      \
        l += (p);                                                          \
    }

    if (beg < end) {
        int idx[4];
#pragma unroll
        for (int i = 0; i < 4; i++) idx[i] = ssrc[beg + 2 * i + half];
        unsigned int hbA[2];
        float pA[2];
#pragma unroll
        for (int i = 0; i < 2; i++) {
            hbA[i] = hv[(size_t)idx[i] * 20 + cl];
            int e = beg + 2 * i + half;
            float p = __expf(lrelu(as2[idx[i]] + adv));
            pA[i] = (e < end) ? p : 0.f;
        }
        for (int j = beg; j < end; j += 8) {
            int idxN[4];
#pragma unroll
            for (int i = 0; i < 4; i++) idxN[i] = ssrc[j + 8 + 2 * i + half];
            unsigned int hbB[2];
            float pB[2];
#pragma unroll
            for (int i = 0; i < 2; i++) {
                hbB[i] = hv[(size_t)idx[2 + i] * 20 + cl];
                int e = j + 4 + 2 * i + half;
                float p = __expf(lrelu(as2[idx[2 + i]] + adv));
                pB[i] = (e < end) ? p : 0.f;
            }
            ACC2(hbA[0], pA[0]);
            ACC2(hbA[1], pA[1]);
#pragma unroll
            for (int i = 0; i < 2; i++) {
                hbA[i] = hv[(size_t)idxN[i] * 20 + cl];
                int e = j + 8 + 2 * i + half;
                float p = __expf(lrelu(as2[idxN[i]] + adv));
                pA[i] = (e < end) ? p : 0.f;
            }
            ACC2(hbB[0], pB[0]);
            ACC2(hbB[1], pB[1]);
#pragma unroll
            for (int i = 0; i < 4; i++) idx[i] = idxN[i];
        }
    }
#undef ACC2
    l += __shfl_xor(l, 32);
    acc[0] += __shfl_xor(acc[0], 32);
    acc[1] += __shfl_xor(acc[1], 32);

    if (half == 0) {
        bool act = hl < 20;
        float inv = 1.f / (l + EPSF);
        float vL = -INFINITY, vH = -INFINITY;
        if (act) {
            float2 b = ((const float2*)b2)[cl];
            vL = acc[0] * inv + b.x;
            vH = acc[1] * inv + b.y;
        }
        float mx = fmaxf(vL, vH);
#pragma unroll
        for (int s = 16; s >= 1; s >>= 1) mx = fmaxf(mx, __shfl_xor(mx, s));
        float ex = act ? (__expf(vL - mx) + __expf(vH - mx)) : 0.f;
#pragma unroll
        for (int s = 16; s >= 1; s >>= 1) ex += __shfl_xor(ex, s);
        if (act) {
            float ls = __logf(ex);
            float2 o = {vL - mx - ls, vH - mx - ls};
            *(float2*)(out + (size_t)node * CLS + cl * 2) = o;
        }
    }
}

// ---------------- launch ----------------

extern "C" void kernel_launch(void* const* d_in, const int* in_sizes, int n_in,
                              void* d_out, int out_size, void* d_ws, size_t ws_size,
                              hipStream_t stream) {
    const float* x    = (const float*)d_in[0];
    const int*   ei   = (const int*)d_in[1];
    const float* W1   = (const float*)d_in[2];
    const float* as1w = (const float*)d_in[3];
    const float* ad1w = (const float*)d_in[4];
    const float* b1   = (const float*)d_in[5];
    const float* W2   = (const float*)d_in[6];
    const float* as2w = (const float*)d_in[7];
    const float* ad2w = (const float*)d_in[8];
    const float* b2   = (const float*)d_in[9];
    float* out = (float*)d_out;

    char* p = (char*)d_ws;
    auto alloc = [&](size_t bytes) {
        char* r = p;
        p += (bytes + 255) & ~(size_t)255;
        return r;
    };
    unsigned char* h1f8 = (unsigned char*)alloc((size_t)NN * C1);
    unsigned short* g1b = (unsigned short*)alloc((size_t)NN * C1 * 2);
    unsigned short* h2b = (unsigned short*)alloc((size_t)NN * CLS * 2);
    float* as1  = (float*)alloc((size_t)NN * 4 * 4);
    float* ad1  = (float*)alloc((size_t)NN * 4 * 4);
    float* as2  = (float*)alloc((size_t)NN * 4);
    float* ad2  = (float*)alloc((size_t)NN * 4);
    int* offs   = (int*)alloc((size_t)(NN + 1024) * 4);  // +pad: bsg writes 98*512 entries
    int* gcur   = (int*)alloc(128 * 4);
    unsigned int* stage = (unsigned int*)alloc((size_t)NB * BSTRIDE * 4);
    int* ssrc   = (int*)alloc((size_t)(NE + 64) * 4);
    unsigned short* wB1 = (unsigned short*)alloc((size_t)4096 * 8 * 2);
    unsigned short* wB2 = (unsigned short*)alloc((size_t)1536 * 8 * 2);

    hipMemsetAsync(gcur, 0, 128 * 4, stream);

    k_bucket<<<NBLK_B, 512, 0, stream>>>(ei, gcur, stage, W1, W2, wB1, wB2, ssrc + NE);
    k_bsg<<<NB + NBLK_G, 512, 0, stream>>>(stage, gcur, offs, ssrc,
                                           x, wB1, as1w, ad1w, h1f8, as1, ad1);
    k_agg1<<<NN / 4, 256, 0, stream>>>(h1f8, as1, ad1, offs, ssrc, b1, g1b);

    k_gemm2<<<(NN + 63) / 64, 256, 0, stream>>>(g1b, wB2, as2w, ad2w, h2b, as2, ad2);
    k_agg2<<<NN / 4, 256, 0, stream>>>(h2b, as2, ad2, offs, ssrc, b2, out);
}

// Round 11
// 195.797 us; speedup vs baseline: 1.0662x; 1.0039x over previous
//
#include <hip/hip_runtime.h>
#include <math.h>

#define NN 50000
#define NE 800000
#define FIN 128
#define HID 64
#define HEADS 4
#define C1 256   // HEADS*HID
#define CLS 40
#define EPSF 1e-16f

// bucket sort params: 98 buckets of 512 dst nodes each
#define NB 98
#define BSH 9
#define BSTRIDE 9216     // > max bucket count (mean 8192, +11 sigma), 64B-aligned
#define NBLK_B 625
#define CHUNK 1280       // 625*1280 == NE exactly. r9 tried 640 (2x blocks):
                         // REGRESSED ~+13us total — halving run length fragments
                         // the stage write-out (write-locality >> block latency).
#define NBLK_G 391       // ceil(50000/128) gemm1 double-tiles

typedef __attribute__((ext_vector_type(8))) short bf16x8;
typedef __attribute__((ext_vector_type(4))) float f32x4;
typedef __attribute__((ext_vector_type(2))) float f32x2;

__device__ __forceinline__ unsigned short f2bf(float f) {
    unsigned int u = __float_as_uint(f);
    unsigned int r = (u + 0x7fffu + ((u >> 16) & 1u)) >> 16;   // RNE
    return (unsigned short)r;
}
__device__ __forceinline__ float bflo(unsigned int u) { return __uint_as_float(u << 16); }
__device__ __forceinline__ float bfhi(unsigned int u) { return __uint_as_float(u & 0xffff0000u); }
__device__ __forceinline__ unsigned char f2fp8(float v) {
    int pk = __builtin_amdgcn_cvt_pk_fp8_f32(v, v, 0, false);
    return (unsigned char)(pk & 0xff);
}
__device__ __forceinline__ float lrelu(float e) { return e > 0.f ? e : 0.2f * e; }

// ---------------- two-level bucket sort of edges by dst ----------------
// Level 1: partition edges into 98 coarse buckets; in-LDS counting sort by
// bucket before the global write so stage writes are coalesced line bursts.
// r11: the 128-bin prefix scan is done by wave 0 via __shfl_up (2 bins/lane,
// barrier-free) instead of a block-wide Hillis-Steele (14 barriers); the
// gcur reservation atomics now overlap the scan.
// Blocks 0..10 additionally perform the one-time W1/W2 -> MFMA-fragment
// conversion; block 0 also zeroes the ssrc tail pad (replaces a memset).
__global__ __launch_bounds__(512) void k_bucket(const int* __restrict__ ei,
                                                int* __restrict__ gcur,
                                                unsigned int* __restrict__ stage,
                                                const float* __restrict__ W1,
                                                const float* __restrict__ W2,
                                                unsigned short* __restrict__ wB1,
                                                unsigned short* __restrict__ wB2,
                                                int* __restrict__ ssrc_pad) {
    __shared__ unsigned int lchunk[CHUNK];
    __shared__ unsigned int lsort[CHUNK];
    __shared__ int lhist[128];
    __shared__ int lstart[128];
    __shared__ int lbase[128];
    __shared__ int lcur[128];
    int t = threadIdx.x;

    // folded-in weight conversion (independent work, overlaps LDS phase)
    if (blockIdx.x < 11) {
        int tw = blockIdx.x * 512 + t;
        if (blockIdx.x == 0 && t >= 448) ssrc_pad[t - 448] = 0;  // ssrc[NE..NE+63]
        if (tw < 4096) {
            int tn = tw >> 8;
            int kc = (tw >> 6) & 3;
            int lw = tw & 63;
            int n = tn * 16 + (lw & 15);
            int k0 = kc * 32 + (lw >> 4) * 8;
            unsigned short* o = wB1 + (size_t)tw * 8;
#pragma unroll
            for (int j = 0; j < 8; j++) o[j] = f2bf(W1[(size_t)(k0 + j) * C1 + n]);
        } else if (tw < 4096 + 1536) {
            int u = tw - 4096;
            int tn = u >> 9;
            int kc = (u >> 6) & 7;
            int lw = u & 63;
            int n = tn * 16 + (lw & 15);
            int k0 = kc * 32 + (lw >> 4) * 8;
            unsigned short* o = wB2 + (size_t)u * 8;
#pragma unroll
            for (int j = 0; j < 8; j++)
                o[j] = (n < CLS) ? f2bf(W2[(size_t)(k0 + j) * CLS + n]) : (unsigned short)0;
        }
    }

    int e0 = blockIdx.x * CHUNK;
    if (t < 128) lhist[t] = 0;
    __syncthreads();
    for (int j = t; j < CHUNK; j += 512) {
        int s = ei[e0 + j];
        int d = ei[NE + e0 + j];
        int b = d >> BSH;
        atomicAdd(&lhist[b], 1);
        lchunk[j] = (unsigned int)s | ((unsigned int)(d & 511) << 16) |
                    ((unsigned int)b << 25);
    }
    __syncthreads();
    // reservation (overlaps the scan below — lhist is final here)
    if (t < NB) lbase[t] = atomicAdd(&gcur[t], lhist[t]);
    // wave-0 barrier-free exclusive scan of the 128 bins (2 bins/lane)
    if (t < 64) {
        int b0 = 2 * t, b1 = 2 * t + 1;
        int h0 = lhist[b0], h1 = lhist[b1];
        int s = h0 + h1;
        int incl = s;
#pragma unroll
        for (int d = 1; d < 64; d <<= 1) {
            int u = __shfl_up(incl, d);
            if (t >= d) incl += u;
        }
        int excl = incl - s;
        lstart[b0] = excl;
        lcur[b0] = excl;
        lstart[b1] = excl + h0;
        lcur[b1] = excl + h0;
    }
    __syncthreads();
    // in-LDS counting sort by bucket
    for (int j = t; j < CHUNK; j += 512) {
        unsigned int pk = lchunk[j];
        int b = pk >> 25;
        int pos = atomicAdd(&lcur[b], 1);
        lsort[pos] = pk;
    }
    __syncthreads();
    // coalesced write-out: consecutive j -> consecutive dest within a run
    for (int j = t; j < CHUNK; j += 512) {
        unsigned int pk = lsort[j];
        int b = pk >> 25;
        int dest = lbase[b] + (j - lstart[b]);
        stage[(size_t)b * BSTRIDE + dest] = pk & 0x01FFFFFFu;
    }
}

// ---------------- fused bsort + gemm1 (independent work, one dispatch) ----
// Blocks 0..NB-1: per-bucket LDS counting sort (bsort body, 512 threads).
// Blocks NB..NB+390: TWO copies of the verified 256-thread gemm1 tile.
// r11: bucket base = wave-0 strided reduce over gcur[0..b) (barrier-free)
// instead of a 128-wide block Hillis-Steele scan.
__global__ __launch_bounds__(512) void k_bsg(const unsigned int* __restrict__ stage,
                                             const int* __restrict__ gcur,
                                             int* __restrict__ offs,
                                             int* __restrict__ ssrc,
                                             const float* __restrict__ x,
                                             const unsigned short* __restrict__ wB,
                                             const float* __restrict__ aws,
                                             const float* __restrict__ awd,
                                             unsigned char* __restrict__ h1f8,
                                             float* __restrict__ as1,
                                             float* __restrict__ ad1) {
    __shared__ union SM {
        struct { int lhist[512]; int cur[512]; int gb; } b;
        struct { uint4 Af[2][4][4][64]; } g;   // 32 KB
    } sm;

    if (blockIdx.x < NB) {
        // ---------------- bsort body ----------------
        int t = threadIdx.x;
        int b = blockIdx.x;
        int cnt = gcur[b];
        const unsigned int* sp = stage + (size_t)b * BSTRIDE;
        sm.b.lhist[t] = 0;
        // bucket base = sum of gcur[0..b): wave-0 strided reduce, no barriers
        if (t < 64) {
            int s = 0;
            for (int k = t; k < b; k += 64) s += gcur[k];
#pragma unroll
            for (int d = 32; d >= 1; d >>= 1) s += __shfl_xor(s, d);
            if (t == 0) sm.b.gb = s;
        }
        __syncthreads();
        int gbase = sm.b.gb;
        for (int j = t; j < cnt; j += 512) atomicAdd(&sm.b.lhist[(sp[j] >> 16) & 511], 1);
        __syncthreads();
        if (t < 64) {
            int base = t * 8;
            int vals[8];
            int run = 0;
#pragma unroll
            for (int j = 0; j < 8; j++) { int v = sm.b.lhist[base + j]; vals[j] = run; run += v; }
            int sc = run;
#pragma unroll
            for (int d = 1; d < 64; d <<= 1) { int u = __shfl_up(sc, d); if (t >= d) sc += u; }
            int excl = sc - run;
#pragma unroll
            for (int j = 0; j < 8; j++) sm.b.cur[base + j] = excl + vals[j];
        }
        __syncthreads();
        offs[(b << BSH) + t] = gbase + sm.b.cur[t];
        __syncthreads();
        for (int j = t; j < cnt; j += 512) {
            unsigned int v = sp[j];
            int dl = (v >> 16) & 511;
            int pos = atomicAdd(&sm.b.cur[dl], 1);
            ssrc[gbase + pos] = (int)(v & 0xFFFFu);
        }
        return;
    }

    // ---------------- gemm1 body (two 64-row tiles per block) ----------------
    int half = threadIdx.x >> 8;
    int t = threadIdx.x & 255;
    int m0 = ((blockIdx.x - NB) * 2 + half) * 64;
    int l = t & 63;
    int wv = t >> 6;                 // wave-quarter within the half = head

    // prefetch the wave's 16 B-fragments (independent; overlap staging)
    bf16x8 bf[4][4];
    const bf16x8* wb = (const bf16x8*)wB + l;
#pragma unroll
    for (int tn = 0; tn < 4; tn++)
#pragma unroll
        for (int kc = 0; kc < 4; kc++)
            bf[tn][kc] = wb[(((wv * 4 + tn) * 4 + kc)) * 64];

#pragma unroll
    for (int i = 0; i < 8; i++) {
        int g = i * 256 + t;
        int row = g >> 5;
        int c4 = g & 31;
        int grow = m0 + row;
        if (grow >= NN) grow = NN - 1;
        float4 v = *(const float4*)(x + (size_t)grow * FIN + c4 * 4);
        uint2 pk;
        pk.x = (unsigned int)f2bf(v.x) | ((unsigned int)f2bf(v.y) << 16);
        pk.y = (unsigned int)f2bf(v.z) | ((unsigned int)f2bf(v.w) << 16);
        int kc = c4 >> 3;
        int rem = (c4 & 7) * 4;
        int q = rem >> 3;
        int hh = (rem >> 2) & 1;
        int ll = q * 16 + (row & 15);
        int mt = row >> 4;
        ((uint2*)&sm.g.Af[half][mt][kc][ll])[hh] = pk;
    }
    __syncthreads();

    int q = l >> 4;
    int c = l & 15;

#pragma unroll
    for (int mt = 0; mt < 4; mt++) {
        bf16x8 a[4];
#pragma unroll
        for (int kc = 0; kc < 4; kc++) a[kc] = *(const bf16x8*)&sm.g.Af[half][mt][kc][l];

        f32x4 acc[4];
#pragma unroll
        for (int tn = 0; tn < 4; tn++) acc[tn] = (f32x4){0.f, 0.f, 0.f, 0.f};
#pragma unroll
        for (int tn = 0; tn < 4; tn++) {
            acc[tn] = __builtin_amdgcn_mfma_f32_16x16x32_bf16(a[0], bf[tn][0], acc[tn], 0, 0, 0);
            acc[tn] = __builtin_amdgcn_mfma_f32_16x16x32_bf16(a[1], bf[tn][1], acc[tn], 0, 0, 0);
            acc[tn] = __builtin_amdgcn_mfma_f32_16x16x32_bf16(a[2], bf[tn][2], acc[tn], 0, 0, 0);
            acc[tn] = __builtin_amdgcn_mfma_f32_16x16x32_bf16(a[3], bf[tn][3], acc[tn], 0, 0, 0);
        }

        int row0 = m0 + mt * 16 + q * 4;
        float ps[4] = {0.f, 0.f, 0.f, 0.f}, pd[4] = {0.f, 0.f, 0.f, 0.f};
#pragma unroll
        for (int tn = 0; tn < 4; tn++) {
            int col = wv * 64 + tn * 16 + c;
            float wsv = aws[col];
            float wdv = awd[col];
#pragma unroll
            for (int r = 0; r < 4; r++) {
                float v = acc[tn][r];
                int row = row0 + r;
                if (row < NN) h1f8[(size_t)row * C1 + col] = f2fp8(v);
                ps[r] = fmaf(v, wsv, ps[r]);
                pd[r] = fmaf(v, wdv, pd[r]);
            }
        }
#pragma unroll
        for (int r = 0; r < 4; r++) {
            float a_ = ps[r], d_ = pd[r];
#pragma unroll
            for (int s = 1; s < 16; s <<= 1) {
                a_ += __shfl_xor(a_, s);
                d_ += __shfl_xor(d_, s);
            }
            int row = row0 + r;
            if (c == 0 && row < NN) {
                as1[row * 4 + wv] = a_;
                ad1[row * 4 + wv] = d_;
            }
        }
    }
}

// ---------------- layer 1 aggregation (fp8 messages, fused edge weights) --
// Round-3-verified structure (43.6-43.7us across r7/r8/r10 = measured floor:
// FETCH ~95MB compulsory L2 fill @ ~2.2TB/s, VALU co-busy 72%). FROZEN —
// r4 (16-lane groups), r6 (head-sliced XCD), r8 (packed FMA: neutral) all
// failed to beat it.
__global__ __launch_bounds__(256) void k_agg1(const unsigned char* __restrict__ h1f8,
                                              const float* __restrict__ as1,
                                              const float* __restrict__ ad1,
                                              const int* __restrict__ offs,
                                              const int* __restrict__ ssrc,
                                              const float* __restrict__ b1,
                                              unsigned short* __restrict__ g1b) {
    int lane = threadIdx.x & 63;
    int half = lane >> 5;
    int hl = lane & 31;          // channel group: ch hl*8..+7
    int head = hl >> 3;
    int node = blockIdx.x * 4 + (threadIdx.x >> 6);
    int beg = offs[node];
    int end = (node + 1 < NN) ? offs[node + 1] : NE;
    float adv = ad1[node * 4 + head];
    float l = 0.f;
    f32x2 acc2[4];
#pragma unroll
    for (int c = 0; c < 4; c++) acc2[c] = (f32x2){0.f, 0.f};
    const uint2* hv = (const uint2*)h1f8;   // 32 uint2 per row

#define ACC1(hb, p)                                                                   \
    {                                                                                 \
        f32x2 pp = {(p), (p)};                                                        \
        acc2[0] = __builtin_elementwise_fma(                                          \
            pp, __builtin_amdgcn_cvt_pk_f32_fp8((hb).x, false), acc2[0]);             \
        acc2[1] = __builtin_elementwise_fma(                                          \
            pp, __builtin_amdgcn_cvt_pk_f32_fp8((hb).x, true), acc2[1]);              \
        acc2[2] = __builtin_elementwise_fma(                                          \
            pp, __builtin_amdgcn_cvt_pk_f32_fp8((hb).y, false), acc2[2]);             \
        acc2[3] = __builtin_elementwise_fma(                                          \
            pp, __builtin_amdgcn_cvt_pk_f32_fp8((hb).y, true), acc2[3]);              \
        l += (p);                                                                     \
    }

    if (beg < end) {
        int idx[4];
#pragma unroll
        for (int i = 0; i < 4; i++) idx[i] = ssrc[beg + 2 * i + half];
        uint2 hbA[2];
        float pA[2];
#pragma unroll
        for (int i = 0; i < 2; i++) {
            hbA[i] = hv[(size_t)idx[i] * 32 + hl];
            int e = beg + 2 * i + half;
            float p = __expf(lrelu(as1[idx[i] * 4 + head] + adv));
            pA[i] = (e < end) ? p : 0.f;
        }
        for (int j = beg; j < end; j += 8) {
            int idxN[4];
#pragma unroll
            for (int i = 0; i < 4; i++) idxN[i] = ssrc[j + 8 + 2 * i + half];
            uint2 hbB[2];
            float pB[2];
#pragma unroll
            for (int i = 0; i < 2; i++) {
                hbB[i] = hv[(size_t)idx[2 + i] * 32 + hl];
                int e = j + 4 + 2 * i + half;
                float p = __expf(lrelu(as1[idx[2 + i] * 4 + head] + adv));
                pB[i] = (e < end) ? p : 0.f;
            }
            ACC1(hbA[0], pA[0]);
            ACC1(hbA[1], pA[1]);
#pragma unroll
            for (int i = 0; i < 2; i++) {
                hbA[i] = hv[(size_t)idxN[i] * 32 + hl];
                int e = j + 8 + 2 * i + half;
                float p = __expf(lrelu(as1[idxN[i] * 4 + head] + adv));
                pA[i] = (e < end) ? p : 0.f;
            }
            ACC1(hbB[0], pB[0]);
            ACC1(hbB[1], pB[1]);
#pragma unroll
            for (int i = 0; i < 4; i++) idx[i] = idxN[i];
        }
    }
#undef ACC1
    // combine the two halves (same channels, disjoint edge subsets)
    l += __shfl_xor(l, 32);
#pragma unroll
    for (int c = 0; c < 4; c++) {
        acc2[c][0] += __shfl_xor(acc2[c][0], 32);
        acc2[c][1] += __shfl_xor(acc2[c][1], 32);
    }

    if (half == 0) {
        float inv = 1.f / (l + EPSF);
        const float4* b1v = (const float4*)b1;
        float4 b0 = b1v[hl * 2];
        float4 b1_ = b1v[hl * 2 + 1];
        float o[8];
        o[0] = fmaxf(fmaf(acc2[0][0], inv, b0.x), 0.f);
        o[1] = fmaxf(fmaf(acc2[0][1], inv, b0.y), 0.f);
        o[2] = fmaxf(fmaf(acc2[1][0], inv, b0.z), 0.f);
        o[3] = fmaxf(fmaf(acc2[1][1], inv, b0.w), 0.f);
        o[4] = fmaxf(fmaf(acc2[2][0], inv, b1_.x), 0.f);
        o[5] = fmaxf(fmaf(acc2[2][1], inv, b1_.y), 0.f);
        o[6] = fmaxf(fmaf(acc2[3][0], inv, b1_.z), 0.f);
        o[7] = fmaxf(fmaf(acc2[3][1], inv, b1_.w), 0.f);
        uint4 ob;
        ob.x = (unsigned int)f2bf(o[0]) | ((unsigned int)f2bf(o[1]) << 16);
        ob.y = (unsigned int)f2bf(o[2]) | ((unsigned int)f2bf(o[3]) << 16);
        ob.z = (unsigned int)f2bf(o[4]) | ((unsigned int)f2bf(o[5]) << 16);
        ob.w = (unsigned int)f2bf(o[6]) | ((unsigned int)f2bf(o[7]) << 16);
        ((uint4*)g1b)[(size_t)node * 32 + hl] = ob;
    }
}

// ---------------- layer 2: bf16 MFMA GEMM + fused alpha2 -----------------
__global__ __launch_bounds__(256) void k_gemm2(const unsigned short* __restrict__ g1b,
                                               const unsigned short* __restrict__ wB2,
                                               const float* __restrict__ aws,
                                               const float* __restrict__ awd,
                                               unsigned short* __restrict__ h2b,
                                               float* __restrict__ as2,
                                               float* __restrict__ ad2) {
    __shared__ uint4 Af[4][8][64];   // [mt][kc][lane], 32 KB
    int t = threadIdx.x;
    int m0 = blockIdx.x * 64;

#pragma unroll
    for (int i = 0; i < 8; i++) {
        int g = i * 256 + t;
        int row = g >> 5;
        int c8 = g & 31;
        int grow = m0 + row;
        if (grow >= NN) grow = NN - 1;
        uint4 v = *(const uint4*)(g1b + (size_t)grow * C1 + c8 * 8);
        int kc = c8 >> 2;
        int q = c8 & 3;
        Af[row >> 4][kc][q * 16 + (row & 15)] = v;
    }
    __syncthreads();

    int l = t & 63;
    int wv = t >> 6;

    bf16x8 a[8];
#pragma unroll
    for (int kc = 0; kc < 8; kc++) a[kc] = *(const bf16x8*)&Af[wv][kc][l];

    f32x4 acc[3];
#pragma unroll
    for (int tn = 0; tn < 3; tn++) acc[tn] = (f32x4){0.f, 0.f, 0.f, 0.f};

    const bf16x8* wb = (const bf16x8*)wB2 + l;
#pragma unroll
    for (int tn = 0; tn < 3; tn++) {
#pragma unroll
        for (int kc = 0; kc < 8; kc++) {
            bf16x8 b = wb[(tn * 8 + kc) * 64];
            acc[tn] = __builtin_amdgcn_mfma_f32_16x16x32_bf16(a[kc], b, acc[tn], 0, 0, 0);
        }
    }

    int q = l >> 4;
    int c = l & 15;
    int row0 = m0 + wv * 16 + q * 4;
    float ps[4] = {0.f, 0.f, 0.f, 0.f}, pd[4] = {0.f, 0.f, 0.f, 0.f};
#pragma unroll
    for (int tn = 0; tn < 3; tn++) {
        int col = tn * 16 + c;
        bool cok = col < CLS;
        float wsv = cok ? aws[col] : 0.f;
        float wdv = cok ? awd[col] : 0.f;
#pragma unroll
        for (int r = 0; r < 4; r++) {
            float v = acc[tn][r];
            int row = row0 + r;
            if (cok && row < NN) h2b[(size_t)row * CLS + col] = f2bf(v);
            ps[r] = fmaf(v, wsv, ps[r]);
            pd[r] = fmaf(v, wdv, pd[r]);
        }
    }
#pragma unroll
    for (int r = 0; r < 4; r++) {
        float a_ = ps[r], d_ = pd[r];
#pragma unroll
        for (int s = 1; s < 16; s <<= 1) {
            a_ += __shfl_xor(a_, s);
            d_ += __shfl_xor(d_, s);
        }
        int row = row0 + r;
        if (c == 0 && row < NN) {
            as2[row] = a_;
            ad2[row] = d_;
        }
    }
}

// ---------------- layer 2 aggregation + fused log_softmax ----------------
// Round-3-verified structure; {bflo,bfhi} packed into one f32x2 FMA.
// r9 tried a 16-edge window: REGRESSED — mean degree is 16, so the wider
// window wastes ~8 masked gathers/node-half (issued traffic, p=0).
__global__ __launch_bounds__(256) void k_agg2(const unsigned short* __restrict__ h2b,
                                              const float* __restrict__ as2,
                                              const float* __restrict__ ad2,
                                              const int* __restrict__ offs,
                                              const int* __restrict__ ssrc,
                                              const float* __restrict__ b2,
                                              float* __restrict__ out) {
    int lane = threadIdx.x & 63;
    int half = lane >> 5;
    int hl = lane & 31;
    int cl = hl < 20 ? hl : 19;   // uint index within row (2 channels)
    int node = blockIdx.x * 4 + (threadIdx.x >> 6);
    int beg = offs[node];
    int end = (node + 1 < NN) ? offs[node + 1] : NE;
    float adv = ad2[node];
    float l = 0.f;
    f32x2 acc = {0.f, 0.f};
    const unsigned int* hv = (const unsigned int*)h2b;   // 20 uints per row

#define ACC2(hb, p)                                                        \
    {                                                                      \
        f32x2 pp = {(p), (p)};                                             \
        f32x2 bf = {bflo(hb), bfhi(hb)};                                   \
        acc = __builtin_elementwise_fma(pp, bf, acc);                      \
        l += (p);                                                          \
    }

    if (beg < end) {
        int idx[4];
#pragma unroll
        for (int i = 0; i < 4; i++) idx[i] = ssrc[beg + 2 * i + half];
        unsigned int hbA[2];
        float pA[2];
#pragma unroll
        for (int i = 0; i < 2; i++) {
            hbA[i] = hv[(size_t)idx[i] * 20 + cl];
            int e = beg + 2 * i + half;
            float p = __expf(lrelu(as2[idx[i]] + adv));
            pA[i] = (e < end) ? p : 0.f;
        }
        for (int j = beg; j < end; j += 8) {
            int idxN[4];
#pragma unroll
            for (int i = 0; i < 4; i++) idxN[i] = ssrc[j + 8 + 2 * i + half];
            unsigned int hbB[2];
            float pB[2];
#pragma unroll
            for (int i = 0; i < 2; i++) {
                hbB[i] = hv[(size_t)idx[2 + i] * 20 + cl];
                int e = j + 4 + 2 * i + half;
                float p = __expf(lrelu(as2[idx[2 + i]] + adv));
                pB[i] = (e < end) ? p : 0.f;
            }
            ACC2(hbA[0], pA[0]);
            ACC2(hbA[1], pA[1]);
#pragma unroll
            for (int i = 0; i < 2; i++) {
                hbA[i] = hv[(size_t)idxN[i] * 20 + cl];
                int e = j + 8 + 2 * i + half;
                float p = __expf(lrelu(as2[idxN[i]] + adv));
                pA[i] = (e < end) ? p : 0.f;
            }
            ACC2(hbB[0], pB[0]);
            ACC2(hbB[1], pB[1]);
#pragma unroll
            for (int i = 0; i < 4; i++) idx[i] = idxN[i];
        }
    }
#undef ACC2
    l += __shfl_xor(l, 32);
    acc[0] += __shfl_xor(acc[0], 32);
    acc[1] += __shfl_xor(acc[1], 32);

    if (half == 0) {
        bool act = hl < 20;
        float inv = 1.f / (l + EPSF);
        float vL = -INFINITY, vH = -INFINITY;
        if (act) {
            float2 b = ((const float2*)b2)[cl];
            vL = acc[0] * inv + b.x;
            vH = acc[1] * inv + b.y;
        }
        float mx = fmaxf(vL, vH);
#pragma unroll
        for (int s = 16; s >= 1; s >>= 1) mx = fmaxf(mx, __shfl_xor(mx, s));
        float ex = act ? (__expf(vL - mx) + __expf(vH - mx)) : 0.f;
#pragma unroll
        for (int s = 16; s >= 1; s >>= 1) ex += __shfl_xor(ex, s);
        if (act) {
            float ls = __logf(ex);
            float2 o = {vL - mx - ls, vH - mx - ls};
            *(float2*)(out + (size_t)node * CLS + cl * 2) = o;
        }
    }
}

// ---------------- launch ----------------

extern "C" void kernel_launch(void* const* d_in, const int* in_sizes, int n_in,
                              void* d_out, int out_size, void* d_ws, size_t ws_size,
                              hipStream_t stream) {
    const float* x    = (const float*)d_in[0];
    const int*   ei   = (const int*)d_in[1];
    const float* W1   = (const float*)d_in[2];
    const float* as1w = (const float*)d_in[3];
    const float* ad1w = (const float*)d_in[4];
    const float* b1   = (const float*)d_in[5];
    const float* W2   = (const float*)d_in[6];
    const float* as2w = (const float*)d_in[7];
    const float* ad2w = (const float*)d_in[8];
    const float* b2   = (const float*)d_in[9];
    float* out = (float*)d_out;

    char* p = (char*)d_ws;
    auto alloc = [&](size_t bytes) {
        char* r = p;
        p += (bytes + 255) & ~(size_t)255;
        return r;
    };
    unsigned char* h1f8 = (unsigned char*)alloc((size_t)NN * C1);
    unsigned short* g1b = (unsigned short*)alloc((size_t)NN * C1 * 2);
    unsigned short* h2b = (unsigned short*)alloc((size_t)NN * CLS * 2);
    float* as1  = (float*)alloc((size_t)NN * 4 * 4);
    float* ad1  = (float*)alloc((size_t)NN * 4 * 4);
    float* as2  = (float*)alloc((size_t)NN * 4);
    float* ad2  = (float*)alloc((size_t)NN * 4);
    int* offs   = (int*)alloc((size_t)(NN + 1024) * 4);  // +pad: bsg writes 98*512 entries
    int* gcur   = (int*)alloc(128 * 4);
    unsigned int* stage = (unsigned int*)alloc((size_t)NB * BSTRIDE * 4);
    int* ssrc   = (int*)alloc((size_t)(NE + 64) * 4);
    unsigned short* wB1 = (unsigned short*)alloc((size_t)4096 * 8 * 2);
    unsigned short* wB2 = (unsigned short*)alloc((size_t)1536 * 8 * 2);

    hipMemsetAsync(gcur, 0, 128 * 4, stream);

    k_bucket<<<NBLK_B, 512, 0, stream>>>(ei, gcur, stage, W1, W2, wB1, wB2, ssrc + NE);
    k_bsg<<<NB + NBLK_G, 512, 0, stream>>>(stage, gcur, offs, ssrc,
                                           x, wB1, as1w, ad1w, h1f8, as1, ad1);
    k_agg1<<<NN / 4, 256, 0, stream>>>(h1f8, as1, ad1, offs, ssrc, b1, g1b);

    k_gemm2<<<(NN + 63) / 64, 256, 0, stream>>>(g1b, wB2, as2w, ad2w, h2b, as2, ad2);
    k_agg2<<<NN / 4, 256, 0, stream>>>(h2b, as2, ad2, offs, ssrc, b2, out);
}